// Round 4
// baseline (466.317 us; speedup 1.0000x reference)
//
#include <hip/hip_runtime.h>

// LJ 12-6 over a neighbor list — round 14: 3D cell filter split by dimension.
// History: R2 direct-gather 131 us (TA wall ~3.1 cy/lane-request at 32
// waves). R10/R12 fused 6x6 xy filter 74 us (16 waves, latency-bound).
// R13 split (xy-filter -> list -> compute): compute=53us@50%occ (TA wall
// ~6cy/req), filter~45-50us (16-wave cap), sum regressed. Lessons: both
// phases are occupancy-starved; xy-only passes 19.75% vs 8.8% for full 3D.
// This round:
//  K1 y-filter+compact: 3-bit y table = 78KB LDS -> 2 WG/CU = 32 waves
//     (launch_bounds(1024,8) caps VGPR at 64). BW-bound idx stream, pass
//     44.4%, one global-atomic per wave per 8-pair group (~32k total).
//  K2 xz-filter+gather+LJ: 6-bit x|z<<3 table = 150KB LDS (16 waves).
//     Combined pass 0.444^3 = 8.8% -> 1.12M pairs -> 2.25M gather requests
//     (2.25x fewer than R12). Zero-select keeps VMEM issue constant.
// Conservative for ANY box/cutoff (cutoff-sized cells, monotone clamp).

typedef int   v4i __attribute__((ext_vector_type(4)));
typedef float v4f __attribute__((ext_vector_type(4)));

#define GRP     8
#define WGT     1024
#define K1_NWG  512    // 2 per CU
#define K2_NWG  256    // 1 per CU
#define NWG_F   256

// ---------------- prep (split path): Rp + packedY (3b/atom) + packedXZ (6b) -
__global__ void __launch_bounds__(256) prep3_kernel(
    const float* __restrict__ R, const float* __restrict__ cut_p,
    v4f* __restrict__ Rp, unsigned* __restrict__ packedY,
    unsigned* __restrict__ packedXZ, int n_atoms)
{
    int t = blockIdx.x * blockDim.x + threadIdx.x;
    int n_grp = (n_atoms + 9) / 10;
    if (t >= n_grp) return;
    const float inv_cut = 1.0f / cut_p[0];
    int a0 = t * 10;
    unsigned wy = 0u, wxz0 = 0u, wxz1 = 0u;
#pragma unroll
    for (int k = 0; k < 10; ++k) {
        int a = a0 + k;
        if (a < n_atoms) {
            float x = R[3 * a + 0];
            float y = R[3 * a + 1];
            float z = R[3 * a + 2];
            v4f v; v.x = x; v.y = y; v.z = z; v.w = 0.0f;
            Rp[a] = v;  // 16B aligned: single-transaction gathers later
            unsigned cx = (unsigned)min(7, max(0, (int)(x * inv_cut)));
            unsigned cy = (unsigned)min(7, max(0, (int)(y * inv_cut)));
            unsigned cz = (unsigned)min(7, max(0, (int)(z * inv_cut)));
            wy |= cy << (3 * k);
            unsigned cxz = cx | (cz << 3);
            if (k < 5) wxz0 |= cxz << (6 * k);
            else       wxz1 |= cxz << (6 * (k - 5));
        }
        // padded atoms keep cell 0; padded pairs (0,0) rejected by r2>1e-10
    }
    packedY[t]          = wy;
    packedXZ[2 * t]     = wxz0;
    packedXZ[2 * t + 1] = wxz1;
}

// ---------------- prep (fused fallback): Rp + packed xy 6b/atom -------------
__global__ void __launch_bounds__(256) prep_kernel(
    const float* __restrict__ R, const float* __restrict__ cut_p,
    v4f* __restrict__ Rp, unsigned* __restrict__ packed, int n_atoms)
{
    int t = blockIdx.x * blockDim.x + threadIdx.x;
    int n_grp = (n_atoms + 4) / 5;
    if (t >= n_grp) return;
    const float inv_cut = 1.0f / cut_p[0];
    int a0 = t * 5;
    unsigned w = 0u;
#pragma unroll
    for (int k = 0; k < 5; ++k) {
        int a = a0 + k;
        if (a < n_atoms) {
            float x = R[3 * a + 0];
            float y = R[3 * a + 1];
            float z = R[3 * a + 2];
            v4f v; v.x = x; v.y = y; v.z = z; v.w = 0.0f;
            Rp[a] = v;
            int cx = min(7, max(0, (int)(x * inv_cut)));
            int cy = min(7, max(0, (int)(y * inv_cut)));
            w |= (unsigned)(cx | (cy << 3)) << (6 * k);
        }
    }
    packed[t] = w;
}

__global__ void __launch_bounds__(256) pad_R_kernel(
    const float* __restrict__ R, v4f* __restrict__ Rp, int n_atoms)
{
    int a = blockIdx.x * blockDim.x + threadIdx.x;
    if (a < n_atoms) {
        v4f v;
        v.x = R[3 * a + 0];
        v.y = R[3 * a + 1];
        v.z = R[3 * a + 2];
        v.w = 0.0f;
        Rp[a] = v;
    }
}

// 3-bit lookup: word = a/10 (magic), shift = (a%10)*3
__device__ __forceinline__ unsigned cell3w(const unsigned* __restrict__ lds32,
                                           unsigned a) {
    unsigned q = __umulhi(a, 0xCCCCCCCDu) >> 3;   // a / 10
    unsigned r = a - q * 10u;                      // a % 10
    return (lds32[q] >> (r * 3u)) & 7u;
}

// 6-bit lookup: word = a/5 (magic), shift = (a%5)*6
__device__ __forceinline__ unsigned cell6w(const unsigned* __restrict__ lds32,
                                           unsigned a) {
    unsigned q = __umulhi(a, 0xCCCCCCCDu) >> 2;   // a / 5
    unsigned r = a - q * 5u;                       // a % 5
    return (lds32[q] >> (r * 6u)) & 63u;
}

__device__ __forceinline__ void load_grp(
    const int* __restrict__ idx_i, const int* __restrict__ idx_j,
    int p, int n_pairs, int* __restrict__ is8, int* __restrict__ js8)
{
    if (p + GRP <= n_pairs) {   // p % 8 == 0 -> int4-aligned fast path
        v4i a0 = __builtin_nontemporal_load((const v4i*)idx_i + (p >> 2));
        v4i a1 = __builtin_nontemporal_load((const v4i*)idx_i + (p >> 2) + 1);
        v4i b0 = __builtin_nontemporal_load((const v4i*)idx_j + (p >> 2));
        v4i b1 = __builtin_nontemporal_load((const v4i*)idx_j + (p >> 2) + 1);
        is8[0] = a0.x; is8[1] = a0.y; is8[2] = a0.z; is8[3] = a0.w;
        is8[4] = a1.x; is8[5] = a1.y; is8[6] = a1.z; is8[7] = a1.w;
        js8[0] = b0.x; js8[1] = b0.y; js8[2] = b0.z; js8[3] = b0.w;
        js8[4] = b1.x; js8[5] = b1.y; js8[6] = b1.z; js8[7] = b1.w;
    } else {
#pragma unroll
        for (int k = 0; k < GRP; ++k) {
            bool v = (p + k < n_pairs);
            is8[k] = v ? idx_i[p + k] : 0;
            js8[k] = v ? idx_j[p + k] : 0;
        }
    }
}

__device__ __forceinline__ void lj_body(
    v4f A, v4f B, float eps, float s2, float cut2, int gi,
    float* __restrict__ energy, float* __restrict__ forces)
{
    const float dx = A.x - B.x, dy = A.y - B.y, dz = A.z - B.z;
    const float r2 = dx * dx + dy * dy + dz * dz;
    if (r2 < cut2 && r2 > 1e-10f) {
        const float inv  = 1.0f / r2;
        const float sr2  = s2 * inv;
        const float sr6  = sr2 * sr2 * sr2;
        const float sr12 = sr6 * sr6;
        const float e    = 2.0f * eps * (sr12 - sr6);              // 0.5 * 4eps
        const float f    = 24.0f * eps * (2.0f * sr12 - sr6) * inv;
        atomicAdd(&energy[gi], e);
        atomicAdd(&forces[3 * gi + 0], f * dx);
        atomicAdd(&forces[3 * gi + 1], f * dy);
        atomicAdd(&forces[3 * gi + 2], f * dz);
    }
}

// ---------------- K1: y-filter + ballot-compact at 32 waves/CU --------------
// 78KB LDS table -> 2 WG/CU; launch_bounds(1024,8) caps VGPR at 64 so both
// WGs are resident. One global atomicAdd per wave per 8-pair group.
__global__ void __launch_bounds__(WGT, 8) filter_y_kernel(
    const unsigned* __restrict__ packedY,
    const int* __restrict__ idx_i,
    const int* __restrict__ idx_j,
    int2* __restrict__ list,
    int* __restrict__ count,
    int n_pairs, int pk3_words)
{
    extern __shared__ unsigned lds[];
    for (int w = threadIdx.x; w < pk3_words; w += WGT)
        lds[w] = packedY[w];
    __syncthreads();

    const int stride = (int)gridDim.x * WGT * GRP;
    int p = ((int)blockIdx.x * WGT + (int)threadIdx.x) * GRP;
    const int n_iter = (n_pairs + stride - 1) / stride;

    for (int it = 0; it < n_iter; ++it, p += stride) {
        const bool v = p < n_pairs;
        int is8[GRP], js8[GRP];
        unsigned m = 0u;
        if (v) {
            load_grp(idx_i, idx_j, p, n_pairs, is8, js8);
#pragma unroll
            for (int k = 0; k < GRP; ++k) {
                int dd = (int)cell3w(lds, (unsigned)is8[k])
                       - (int)cell3w(lds, (unsigned)js8[k]);
                if ((unsigned)(dd + 1) <= 2u) m |= (1u << k);
            }
        }

        // wave-level compaction (all lanes participate in ballots)
        int tot = 0;
        int pre[GRP];
#pragma unroll
        for (int k = 0; k < GRP; ++k) {
            unsigned long long bal = __ballot((m >> k) & 1u);
            int before = __builtin_amdgcn_mbcnt_hi(
                (unsigned)(bal >> 32),
                __builtin_amdgcn_mbcnt_lo((unsigned)bal, 0u));
            pre[k] = tot + before;
            tot   += (int)__popcll(bal);
        }

        int wb = 0;
        if (tot > 0) {
            if ((threadIdx.x & 63u) == 0u)
                wb = atomicAdd(count, tot);       // ~32k total across chip
            wb = __shfl(wb, 0, 64);
#pragma unroll
            for (int k = 0; k < GRP; ++k)
                if ((m >> k) & 1u) {
                    int2 pr; pr.x = is8[k]; pr.y = js8[k];
                    list[wb + pre[k]] = pr;
                }
        }
    }
}

// ---------------- K2: xz-filter + gather + LJ (150KB table, 16 waves) -------
__global__ void __launch_bounds__(WGT, 4) lj_xz_kernel(
    const v4f* __restrict__ Rp,
    const unsigned* __restrict__ packedXZ,
    const int2* __restrict__ list,
    const int* __restrict__ count,
    const float* __restrict__ eps_p,
    const float* __restrict__ sig_p,
    const float* __restrict__ cut_p,
    float* __restrict__ energy,
    float* __restrict__ forces,
    int pkxz_words)
{
    extern __shared__ unsigned lds[];
    for (int w = threadIdx.x; w < pkxz_words; w += WGT)
        lds[w] = packedXZ[w];
    __syncthreads();

    const int   cnt  = *count;
    const float eps  = eps_p[0];
    const float sig  = sig_p[0];
    const float cut  = cut_p[0];
    const float s2   = sig * sig;
    const float cut2 = cut * cut;

    const int stride = (int)gridDim.x * WGT * GRP;

    for (int b = ((int)blockIdx.x * WGT + (int)threadIdx.x) * GRP;
         b < cnt; b += stride) {
        int2 pr[GRP];
        if (b + GRP <= cnt) {   // list base 256-aligned, b % 8 == 0
            v4i q0 = __builtin_nontemporal_load((const v4i*)list + (b >> 1));
            v4i q1 = __builtin_nontemporal_load((const v4i*)list + (b >> 1) + 1);
            v4i q2 = __builtin_nontemporal_load((const v4i*)list + (b >> 1) + 2);
            v4i q3 = __builtin_nontemporal_load((const v4i*)list + (b >> 1) + 3);
            pr[0].x = q0.x; pr[0].y = q0.y; pr[1].x = q0.z; pr[1].y = q0.w;
            pr[2].x = q1.x; pr[2].y = q1.y; pr[3].x = q1.z; pr[3].y = q1.w;
            pr[4].x = q2.x; pr[4].y = q2.y; pr[5].x = q2.z; pr[5].y = q2.w;
            pr[6].x = q3.x; pr[6].y = q3.y; pr[7].x = q3.z; pr[7].y = q3.w;
        } else {
#pragma unroll
            for (int k = 0; k < GRP; ++k) {
                if (b + k < cnt) pr[k] = list[b + k];
                else { pr[k].x = 0; pr[k].y = 0; }  // unwritten ws never read
            }
        }

        // xz-filter; failing pairs -> (0,0): broadcast gather of Rp[0],
        // r2=0 -> rejected. Constant VMEM issue count.
#pragma unroll
        for (int k = 0; k < GRP; ++k) {
            unsigned ci = cell6w(lds, (unsigned)pr[k].x);
            unsigned cj = cell6w(lds, (unsigned)pr[k].y);
            int ddx = (int)(ci & 7u) - (int)(cj & 7u);
            int ddz = (int)(ci >> 3) - (int)(cj >> 3);
            bool ok = ((unsigned)(ddx + 1) <= 2u) & ((unsigned)(ddz + 1) <= 2u);
            pr[k].x = ok ? pr[k].x : 0;
            pr[k].y = ok ? pr[k].y : 0;
        }

        v4f Ri[GRP], Rj[GRP];
#pragma unroll
        for (int k = 0; k < GRP; ++k) { Ri[k] = Rp[pr[k].x]; Rj[k] = Rp[pr[k].y]; }

#pragma unroll
        for (int k = 0; k < GRP; ++k)
            lj_body(Ri[k], Rj[k], eps, s2, cut2, pr[k].x, energy, forces);
    }
}

// ---------------- fallback A: R12 fused kernel ------------------------------
__device__ __forceinline__ void filt_sel(const unsigned* __restrict__ lds32,
                                         int* __restrict__ is8,
                                         int* __restrict__ js8)
{
#pragma unroll
    for (int k = 0; k < GRP; ++k) {
        unsigned ci = cell6w(lds32, (unsigned)is8[k]);
        unsigned cj = cell6w(lds32, (unsigned)js8[k]);
        int ddx = (int)(ci & 7u) - (int)(cj & 7u);
        int ddy = (int)(ci >> 3) - (int)(cj >> 3);
        bool ok = ((unsigned)(ddx + 1) <= 2u) & ((unsigned)(ddy + 1) <= 2u);
        is8[k] = ok ? is8[k] : 0;
        js8[k] = ok ? js8[k] : 0;
    }
}

__global__ void __launch_bounds__(WGT, 4) lj_fused_kernel(
    const v4f* __restrict__ Rp,
    const unsigned* __restrict__ packed,
    const int* __restrict__ idx_i,
    const int* __restrict__ idx_j,
    const float* __restrict__ eps_p,
    const float* __restrict__ sig_p,
    const float* __restrict__ cut_p,
    float* __restrict__ energy,
    float* __restrict__ forces,
    int n_pairs, int pk_words, int chunk)
{
    extern __shared__ unsigned lds[];
    for (int w = threadIdx.x; w < pk_words; w += WGT)
        lds[w] = packed[w];
    __syncthreads();

    const float eps  = eps_p[0];
    const float sig  = sig_p[0];
    const float cut  = cut_p[0];
    const float s2   = sig * sig;
    const float cut2 = cut * cut;

    const int cs = blockIdx.x * chunk;
    const int ce = min(cs + chunk, n_pairs);
    const int STRIDE = WGT * GRP;

    int p0 = cs + (int)threadIdx.x * GRP;
    if (p0 >= ce) return;

    int isA[GRP], jsA[GRP], isB[GRP], jsB[GRP];
    load_grp(idx_i, idx_j, p0, n_pairs, isA, jsA);
    filt_sel(lds, isA, jsA);
    int p1 = p0 + STRIDE;

    while (true) {
        const bool h1 = p1 < ce;
        if (h1) load_grp(idx_i, idx_j, p1, n_pairs, isB, jsB);
        v4f Ri[GRP], Rj[GRP];
#pragma unroll
        for (int k = 0; k < GRP; ++k) { Ri[k] = Rp[isA[k]]; Rj[k] = Rp[jsA[k]]; }
        if (h1) filt_sel(lds, isB, jsB);
#pragma unroll
        for (int k = 0; k < GRP; ++k)
            lj_body(Ri[k], Rj[k], eps, s2, cut2, isA[k], energy, forces);
        if (!h1) break;
#pragma unroll
        for (int k = 0; k < GRP; ++k) { isA[k] = isB[k]; jsA[k] = jsB[k]; }
        p1 += STRIDE;
    }
}

// ---------------- fallback B: R2 structure ----------------------------------
#define PPT 8
__global__ void __launch_bounds__(256) lj_pairs_fb_kernel(
    const v4f* __restrict__ Rp,
    const v4i* __restrict__ idx_i4, const v4i* __restrict__ idx_j4,
    const float* __restrict__ eps_p, const float* __restrict__ sig_p,
    const float* __restrict__ cut_p,
    float* __restrict__ energy, float* __restrict__ forces, int n_oct)
{
    int t = blockIdx.x * blockDim.x + threadIdx.x;
    if (t >= n_oct) return;
    const float eps  = eps_p[0];
    const float sig  = sig_p[0];
    const float cut  = cut_p[0];
    const float s2   = sig * sig;
    const float cut2 = cut * cut;
    v4i ii0 = __builtin_nontemporal_load(idx_i4 + 2 * t);
    v4i ii1 = __builtin_nontemporal_load(idx_i4 + 2 * t + 1);
    v4i jj0 = __builtin_nontemporal_load(idx_j4 + 2 * t);
    v4i jj1 = __builtin_nontemporal_load(idx_j4 + 2 * t + 1);
    int is[PPT] = { ii0.x, ii0.y, ii0.z, ii0.w, ii1.x, ii1.y, ii1.z, ii1.w };
    int js[PPT] = { jj0.x, jj0.y, jj0.z, jj0.w, jj1.x, jj1.y, jj1.z, jj1.w };
    v4f Ri[PPT], Rj[PPT];
#pragma unroll
    for (int k = 0; k < PPT; ++k) Ri[k] = Rp[is[k]];
#pragma unroll
    for (int k = 0; k < PPT; ++k) Rj[k] = Rp[js[k]];
#pragma unroll
    for (int k = 0; k < PPT; ++k)
        lj_body(Ri[k], Rj[k], eps, s2, cut2, is[k], energy, forces);
}

__global__ void lj_pairs_fb_tail_kernel(
    const v4f* __restrict__ Rp,
    const int* __restrict__ idx_i, const int* __restrict__ idx_j,
    const float* __restrict__ eps_p, const float* __restrict__ sig_p,
    const float* __restrict__ cut_p,
    float* __restrict__ energy, float* __restrict__ forces,
    int start, int n_pairs)
{
    int p = start + blockIdx.x * blockDim.x + threadIdx.x;
    if (p >= n_pairs) return;
    const float eps = eps_p[0];
    const float sig = sig_p[0];
    const float cut = cut_p[0];
    lj_body(Rp[idx_i[p]], Rp[idx_j[p]], eps, sig * sig, cut * cut,
            idx_i[p], energy, forces);
}
// -----------------------------------------------------------------------------

extern "C" void kernel_launch(void* const* d_in, const int* in_sizes, int n_in,
                              void* d_out, int out_size, void* d_ws, size_t ws_size,
                              hipStream_t stream) {
    const float* R     = (const float*)d_in[0];
    const float* eps_p = (const float*)d_in[1];
    const float* sig_p = (const float*)d_in[2];
    const float* cut_p = (const float*)d_in[3];
    const int*   idx_i = (const int*)d_in[4];
    const int*   idx_j = (const int*)d_in[5];

    const int n_atoms = in_sizes[0] / 3;
    const int n_pairs = in_sizes[4];

    float* energy = (float*)d_out;
    float* forces = (float*)d_out + n_atoms;

    // d_out re-poisoned 0xAA before every timed call — zero it.
    (void)hipMemsetAsync(d_out, 0, (size_t)out_size * sizeof(float), stream);

    // split-path ws layout: [Rp][packedY][packedXZ][count][list]
    char* ws = (char*)d_ws;
    const size_t rp_b       = (((size_t)n_atoms * 16) + 255) & ~(size_t)255;
    const int    pk3_words  = (n_atoms + 9) / 10;
    const int    pkxz_words = 2 * pk3_words;
    const size_t pk3_b      = (((size_t)pk3_words * 4) + 255) & ~(size_t)255;
    const size_t pkxz_b     = (((size_t)pkxz_words * 4) + 255) & ~(size_t)255;
    const size_t cnt_b      = 256;
    const size_t list_b     = (size_t)n_pairs * 8;
    const size_t ldsY_b     = (((size_t)pk3_words * 4) + 15) & ~(size_t)15;
    const size_t ldsXZ_b    = (((size_t)pkxz_words * 4) + 15) & ~(size_t)15;

    // fused-fallback ws layout: [Rp][packed xy]
    const int    pk_words   = (n_atoms + 4) / 5;
    const size_t pk_b       = (((size_t)pk_words * 4) + 255) & ~(size_t)255;
    const size_t ldsF_b     = (((size_t)pk_words * 4) + 15) & ~(size_t)15;

    const bool have_rp   = ws_size >= rp_b;
    const bool use_split = have_rp
        && (ldsY_b <= 160 * 1024) && (ldsXZ_b <= 160 * 1024)
        && (ws_size >= rp_b + pk3_b + pkxz_b + cnt_b + list_b);
    const bool use_fused = !use_split && have_rp
        && (ldsF_b <= 160 * 1024) && (ws_size >= rp_b + pk_b);

    if (use_split) {
        v4f*      Rp       = (v4f*)ws;
        unsigned* packedY  = (unsigned*)(ws + rp_b);
        unsigned* packedXZ = (unsigned*)(ws + rp_b + pk3_b);
        int*      count    = (int*)(ws + rp_b + pk3_b + pkxz_b);
        int2*     list     = (int2*)(ws + rp_b + pk3_b + pkxz_b + cnt_b);

        (void)hipMemsetAsync(count, 0, sizeof(int), stream);

        int pblocks = ((n_atoms + 9) / 10 + 255) / 256;
        prep3_kernel<<<pblocks, 256, 0, stream>>>(
            R, cut_p, Rp, packedY, packedXZ, n_atoms);

        (void)hipFuncSetAttribute((const void*)filter_y_kernel,
                                  hipFuncAttributeMaxDynamicSharedMemorySize,
                                  (int)ldsY_b);
        filter_y_kernel<<<K1_NWG, WGT, ldsY_b, stream>>>(
            packedY, idx_i, idx_j, list, count, n_pairs, pk3_words);

        (void)hipFuncSetAttribute((const void*)lj_xz_kernel,
                                  hipFuncAttributeMaxDynamicSharedMemorySize,
                                  (int)ldsXZ_b);
        lj_xz_kernel<<<K2_NWG, WGT, ldsXZ_b, stream>>>(
            Rp, packedXZ, list, count, eps_p, sig_p, cut_p,
            energy, forces, pkxz_words);
    } else if (use_fused) {
        v4f*      Rp     = (v4f*)ws;
        unsigned* packed = (unsigned*)(ws + rp_b);

        int pblocks = (pk_words + 255) / 256;
        prep_kernel<<<pblocks, 256, 0, stream>>>(R, cut_p, Rp, packed, n_atoms);

        (void)hipFuncSetAttribute((const void*)lj_fused_kernel,
                                  hipFuncAttributeMaxDynamicSharedMemorySize,
                                  (int)ldsF_b);
        int chunk = (((n_pairs + NWG_F - 1) / NWG_F) + GRP - 1) & ~(GRP - 1);
        lj_fused_kernel<<<NWG_F, WGT, ldsF_b, stream>>>(
            Rp, packed, idx_i, idx_j, eps_p, sig_p, cut_p,
            energy, forces, n_pairs, pk_words, chunk);
    } else if (have_rp) {
        v4f* Rp = (v4f*)ws;
        int blocks = (n_atoms + 255) / 256;
        pad_R_kernel<<<blocks, 256, 0, stream>>>(R, Rp, n_atoms);
        const int n_oct = n_pairs / PPT;
        const int start = n_oct * PPT;
        if (n_oct > 0) {
            int fblocks = (n_oct + 255) / 256;
            lj_pairs_fb_kernel<<<fblocks, 256, 0, stream>>>(
                Rp, (const v4i*)idx_i, (const v4i*)idx_j,
                eps_p, sig_p, cut_p, energy, forces, n_oct);
        }
        if (start < n_pairs) {
            lj_pairs_fb_tail_kernel<<<1, 64, 0, stream>>>(
                Rp, idx_i, idx_j, eps_p, sig_p, cut_p,
                energy, forces, start, n_pairs);
        }
    }
}

// Round 5
// 221.394 us; speedup vs baseline: 2.1063x; 2.1063x over previous
//
#include <hip/hip_runtime.h>

// LJ 12-6 over a neighbor list — round 15: three 32-wave stages, in-place
// compaction, zero global atomics.
// History: R2 direct-gather 131 us (TA wall ~3.1cy/16B divergent request).
// R10/R12 fused xy filter 74 us (150KB LDS -> 16 waves, latency-bound;
// compiler won't pipeline deeper, VGPR pinned 64). R13 split: filter ~35us
// (per-block regions, LDS cursor) + compute 53us. R14 y-filter with ONE
// global atomic counter: 297us (VALU 3.9%, occ 67% -> waves blocked on
// ~25.6k serialized same-line returning atomics ~= 280us). Lessons:
//  (1) every kernel must run 2 WG/CU (3-bit table = 78KB LDS);
//  (2) compaction ordering must be per-block LDS cursor ONLY;
//  (3) 16-wave latency-chained kernels cost ~50-75us no matter the work.
// This round: K1 y-filter -> regions; K2 x-filter IN PLACE (barrier-per-iter
// schedule: reads of iter t complete before claims; cumulative writes <=
// pairs read <= next read base -> writes never overtake unread data);
// K3 z-filter + zero-select gather + LJ (2.3M requests vs R10's 5.06M).
// Cells of size cutoff, clamped 0..7; clamp monotone -> conservative for
// ANY box/cutoff. (0,0) pairs -> r2=0 -> rejected by r2>1e-10.

typedef int   v4i __attribute__((ext_vector_type(4)));
typedef float v4f __attribute__((ext_vector_type(4)));

#define GRP     8
#define GRP3    2
#define WGT     1024
#define NWG_S   512    // split-path grid: 2 WG/CU
#define NWG_F   256

// ---------------- prep (split): Rp + three 3-bit tables (10 atoms/word) ----
__global__ void __launch_bounds__(256) prep3_kernel(
    const float* __restrict__ R, const float* __restrict__ cut_p,
    v4f* __restrict__ Rp, unsigned* __restrict__ pkY,
    unsigned* __restrict__ pkX, unsigned* __restrict__ pkZ, int n_atoms)
{
    int t = blockIdx.x * blockDim.x + threadIdx.x;
    int n_grp = (n_atoms + 9) / 10;
    if (t >= n_grp) return;
    const float inv_cut = 1.0f / cut_p[0];
    int a0 = t * 10;
    unsigned wy = 0u, wx = 0u, wz = 0u;
#pragma unroll
    for (int k = 0; k < 10; ++k) {
        int a = a0 + k;
        if (a < n_atoms) {
            float x = R[3 * a + 0];
            float y = R[3 * a + 1];
            float z = R[3 * a + 2];
            v4f v; v.x = x; v.y = y; v.z = z; v.w = 0.0f;
            Rp[a] = v;  // 16B aligned: single-transaction gathers later
            unsigned cx = (unsigned)min(7, max(0, (int)(x * inv_cut)));
            unsigned cy = (unsigned)min(7, max(0, (int)(y * inv_cut)));
            unsigned cz = (unsigned)min(7, max(0, (int)(z * inv_cut)));
            wx |= cx << (3 * k);
            wy |= cy << (3 * k);
            wz |= cz << (3 * k);
        }
        // padded atoms keep cell 0; (0,0) pairs rejected by r2>1e-10
    }
    pkY[t] = wy;
    pkX[t] = wx;
    pkZ[t] = wz;
}

// ---------------- prep (fused fallback): Rp + packed xy 6b/atom -------------
__global__ void __launch_bounds__(256) prep_kernel(
    const float* __restrict__ R, const float* __restrict__ cut_p,
    v4f* __restrict__ Rp, unsigned* __restrict__ packed, int n_atoms)
{
    int t = blockIdx.x * blockDim.x + threadIdx.x;
    int n_grp = (n_atoms + 4) / 5;
    if (t >= n_grp) return;
    const float inv_cut = 1.0f / cut_p[0];
    int a0 = t * 5;
    unsigned w = 0u;
#pragma unroll
    for (int k = 0; k < 5; ++k) {
        int a = a0 + k;
        if (a < n_atoms) {
            float x = R[3 * a + 0];
            float y = R[3 * a + 1];
            float z = R[3 * a + 2];
            v4f v; v.x = x; v.y = y; v.z = z; v.w = 0.0f;
            Rp[a] = v;
            int cx = min(7, max(0, (int)(x * inv_cut)));
            int cy = min(7, max(0, (int)(y * inv_cut)));
            w |= (unsigned)(cx | (cy << 3)) << (6 * k);
        }
    }
    packed[t] = w;
}

__global__ void __launch_bounds__(256) pad_R_kernel(
    const float* __restrict__ R, v4f* __restrict__ Rp, int n_atoms)
{
    int a = blockIdx.x * blockDim.x + threadIdx.x;
    if (a < n_atoms) {
        v4f v;
        v.x = R[3 * a + 0];
        v.y = R[3 * a + 1];
        v.z = R[3 * a + 2];
        v.w = 0.0f;
        Rp[a] = v;
    }
}

// 3-bit lookup: word = a/10 (magic), shift = (a%10)*3
__device__ __forceinline__ unsigned cell3w(const unsigned* __restrict__ lds32,
                                           unsigned a) {
    unsigned q = __umulhi(a, 0xCCCCCCCDu) >> 3;   // a / 10
    unsigned r = a - q * 10u;                      // a % 10
    return (lds32[q] >> (r * 3u)) & 7u;
}

// 6-bit lookup: word = a/5 (magic), shift = (a%5)*6
__device__ __forceinline__ unsigned cell6w(const unsigned* __restrict__ lds32,
                                           unsigned a) {
    unsigned q = __umulhi(a, 0xCCCCCCCDu) >> 2;   // a / 5
    unsigned r = a - q * 5u;                       // a % 5
    return (lds32[q] >> (r * 6u)) & 63u;
}

__device__ __forceinline__ void load_grp(
    const int* __restrict__ idx_i, const int* __restrict__ idx_j,
    int p, int n_pairs, int* __restrict__ is8, int* __restrict__ js8)
{
    if (p + GRP <= n_pairs) {   // p % 8 == 0 -> int4-aligned fast path
        v4i a0 = __builtin_nontemporal_load((const v4i*)idx_i + (p >> 2));
        v4i a1 = __builtin_nontemporal_load((const v4i*)idx_i + (p >> 2) + 1);
        v4i b0 = __builtin_nontemporal_load((const v4i*)idx_j + (p >> 2));
        v4i b1 = __builtin_nontemporal_load((const v4i*)idx_j + (p >> 2) + 1);
        is8[0] = a0.x; is8[1] = a0.y; is8[2] = a0.z; is8[3] = a0.w;
        is8[4] = a1.x; is8[5] = a1.y; is8[6] = a1.z; is8[7] = a1.w;
        js8[0] = b0.x; js8[1] = b0.y; js8[2] = b0.z; js8[3] = b0.w;
        js8[4] = b1.x; js8[5] = b1.y; js8[6] = b1.z; js8[7] = b1.w;
    } else {
#pragma unroll
        for (int k = 0; k < GRP; ++k) {
            bool v = (p + k < n_pairs);
            is8[k] = v ? idx_i[p + k] : 0;
            js8[k] = v ? idx_j[p + k] : 0;
        }
    }
}

__device__ __forceinline__ void lj_body(
    v4f A, v4f B, float eps, float s2, float cut2, int gi,
    float* __restrict__ energy, float* __restrict__ forces)
{
    const float dx = A.x - B.x, dy = A.y - B.y, dz = A.z - B.z;
    const float r2 = dx * dx + dy * dy + dz * dz;
    if (r2 < cut2 && r2 > 1e-10f) {
        const float inv  = 1.0f / r2;
        const float sr2  = s2 * inv;
        const float sr6  = sr2 * sr2 * sr2;
        const float sr12 = sr6 * sr6;
        const float e    = 2.0f * eps * (sr12 - sr6);              // 0.5 * 4eps
        const float f    = 24.0f * eps * (2.0f * sr12 - sr6) * inv;
        atomicAdd(&energy[gi], e);
        atomicAdd(&forces[3 * gi + 0], f * dx);
        atomicAdd(&forces[3 * gi + 1], f * dy);
        atomicAdd(&forces[3 * gi + 2], f * dz);
    }
}

// wave-level compaction prefix from an 8-bit per-lane mask
__device__ __forceinline__ int wave_prefix(unsigned m, int* __restrict__ pre) {
    int tot = 0;
#pragma unroll
    for (int k = 0; k < GRP; ++k) {
        unsigned long long bal = __ballot((m >> k) & 1u);
        int before = __builtin_amdgcn_mbcnt_hi(
            (unsigned)(bal >> 32),
            __builtin_amdgcn_mbcnt_lo((unsigned)bal, 0u));
        pre[k] = tot + before;
        tot   += (int)__popcll(bal);
    }
    return tot;
}

// ---------------- K1: y-filter -> per-block region + LDS cursor -------------
__global__ void __launch_bounds__(WGT, 8) filter_y_kernel(
    const unsigned* __restrict__ pkY,
    const int* __restrict__ idx_i,
    const int* __restrict__ idx_j,
    int2* __restrict__ list,
    int* __restrict__ counts1,
    int n_pairs, int pk3_words, int chunk)
{
    extern __shared__ unsigned lds[];
    unsigned* cursor = &lds[pk3_words];
    for (int w = threadIdx.x; w < pk3_words; w += WGT)
        lds[w] = pkY[w];
    if (threadIdx.x == 0) *cursor = 0u;
    __syncthreads();

    const int g  = blockIdx.x;
    const int cs = g * chunk;
    const int ce = min(cs + chunk, n_pairs);
    int2* out = list + (size_t)g * (size_t)chunk;
    const int S = WGT * GRP;
    const int n_iter = (ce > cs) ? (ce - cs + S - 1) / S : 0;

    int p = cs + (int)threadIdx.x * GRP;
    for (int it = 0; it < n_iter; ++it, p += S) {
        int is8[GRP], js8[GRP];
        unsigned m = 0u;
        if (p < ce) {   // cs,ce multiples of 8 -> group all-or-nothing
            load_grp(idx_i, idx_j, p, n_pairs, is8, js8);
#pragma unroll
            for (int k = 0; k < GRP; ++k) {
                int dd = (int)cell3w(lds, (unsigned)is8[k])
                       - (int)cell3w(lds, (unsigned)js8[k]);
                if ((unsigned)(dd + 1) <= 2u) m |= (1u << k);
            }
        }
        int pre[GRP];
        int tot = wave_prefix(m, pre);

        unsigned wb = 0u;
        if ((threadIdx.x & 63u) == 0u)
            wb = atomicAdd(cursor, (unsigned)tot);   // LDS atomic only
        wb = (unsigned)__shfl((int)wb, 0, 64);
#pragma unroll
        for (int k = 0; k < GRP; ++k)
            if ((m >> k) & 1u) {
                int2 pr; pr.x = is8[k]; pr.y = js8[k];
                out[wb + (unsigned)pre[k]] = pr;
            }
    }
    __syncthreads();
    if (threadIdx.x == 0) counts1[g] = (int)*cursor;
}

// ---------------- K2: x-filter, IN-PLACE region compaction ------------------
// Safety: per iteration, ALL reads complete before any claim (__syncthreads
// between filter and claim). Cumulative writes <= pairs read so far <= next
// iteration's read base, so writes never overtake unread data.
__global__ void __launch_bounds__(WGT, 8) filter_x_kernel(
    const unsigned* __restrict__ pkX,
    int2* __restrict__ list,
    const int* __restrict__ counts1,
    int* __restrict__ counts2,
    int pk3_words, int chunk)
{
    extern __shared__ unsigned lds[];
    unsigned* cursor = &lds[pk3_words];
    for (int w = threadIdx.x; w < pk3_words; w += WGT)
        lds[w] = pkX[w];
    if (threadIdx.x == 0) *cursor = 0u;
    __syncthreads();

    const int g   = blockIdx.x;
    const int cnt = counts1[g];
    int2* seg = list + (size_t)g * (size_t)chunk;
    const int S = WGT * GRP;
    const int n_iter = (cnt + S - 1) / S;

    int p = (int)threadIdx.x * GRP;
    for (int it = 0; it < n_iter; ++it, p += S) {
        int2 pr[GRP];
        unsigned m = 0u;
        if (p < cnt) {
            if (p + GRP <= cnt) {   // p%8==0, seg 16B-aligned
                v4i q0 = *((const v4i*)seg + (p >> 1));
                v4i q1 = *((const v4i*)seg + (p >> 1) + 1);
                v4i q2 = *((const v4i*)seg + (p >> 1) + 2);
                v4i q3 = *((const v4i*)seg + (p >> 1) + 3);
                pr[0].x = q0.x; pr[0].y = q0.y; pr[1].x = q0.z; pr[1].y = q0.w;
                pr[2].x = q1.x; pr[2].y = q1.y; pr[3].x = q1.z; pr[3].y = q1.w;
                pr[4].x = q2.x; pr[4].y = q2.y; pr[5].x = q2.z; pr[5].y = q2.w;
                pr[6].x = q3.x; pr[6].y = q3.y; pr[7].x = q3.z; pr[7].y = q3.w;
#pragma unroll
                for (int k = 0; k < GRP; ++k) {
                    int dd = (int)cell3w(lds, (unsigned)pr[k].x)
                           - (int)cell3w(lds, (unsigned)pr[k].y);
                    if ((unsigned)(dd + 1) <= 2u) m |= (1u << k);
                }
            } else {
#pragma unroll
                for (int k = 0; k < GRP; ++k) {
                    if (p + k < cnt) {
                        pr[k] = seg[p + k];
                        int dd = (int)cell3w(lds, (unsigned)pr[k].x)
                               - (int)cell3w(lds, (unsigned)pr[k].y);
                        if ((unsigned)(dd + 1) <= 2u) m |= (1u << k);
                    } else { pr[k].x = 0; pr[k].y = 0; }
                }
            }
        }

        __syncthreads();   // all reads of this iter done before any write

        int pre[GRP];
        int tot = wave_prefix(m, pre);
        unsigned wb = 0u;
        if ((threadIdx.x & 63u) == 0u)
            wb = atomicAdd(cursor, (unsigned)tot);   // LDS atomic only
        wb = (unsigned)__shfl((int)wb, 0, 64);
#pragma unroll
        for (int k = 0; k < GRP; ++k)
            if ((m >> k) & 1u)
                seg[wb + (unsigned)pre[k]] = pr[k];
    }
    __syncthreads();
    if (threadIdx.x == 0) counts2[g] = (int)*cursor;
}

// ---------------- K3: z-filter + zero-select gather + LJ at 32 waves --------
// GRP3=2 keeps live VGPRs (~30) under the launch_bounds(1024,8) 32-reg cap.
__global__ void __launch_bounds__(WGT, 8) lj_z_kernel(
    const unsigned* __restrict__ pkZ,
    const v4f* __restrict__ Rp,
    const int2* __restrict__ list,
    const int* __restrict__ counts2,
    const float* __restrict__ eps_p,
    const float* __restrict__ sig_p,
    const float* __restrict__ cut_p,
    float* __restrict__ energy,
    float* __restrict__ forces,
    int pk3_words, int chunk)
{
    extern __shared__ unsigned lds[];
    for (int w = threadIdx.x; w < pk3_words; w += WGT)
        lds[w] = pkZ[w];
    __syncthreads();

    const int g   = blockIdx.x;
    const int cnt = counts2[g];
    const int2* seg = list + (size_t)g * (size_t)chunk;

    const float eps  = eps_p[0];
    const float sig  = sig_p[0];
    const float cut  = cut_p[0];
    const float s2   = sig * sig;
    const float cut2 = cut * cut;

    const int S = WGT * GRP3;
    for (int b = (int)threadIdx.x * GRP3; b < cnt; b += S) {
        int2 pr[GRP3];
        if (b + GRP3 <= cnt) {    // b even, seg 16B-aligned
            v4i q = *((const v4i*)seg + (b >> 1));
            pr[0].x = q.x; pr[0].y = q.y;
            pr[1].x = q.z; pr[1].y = q.w;
        } else {
            pr[0] = seg[b];
            pr[1].x = 0; pr[1].y = 0;
        }
        // z-filter; fails -> (0,0): broadcast gather of Rp[0], r2=0 rejected.
#pragma unroll
        for (int k = 0; k < GRP3; ++k) {
            int dd = (int)cell3w(lds, (unsigned)pr[k].x)
                   - (int)cell3w(lds, (unsigned)pr[k].y);
            bool ok = (unsigned)(dd + 1) <= 2u;
            pr[k].x = ok ? pr[k].x : 0;
            pr[k].y = ok ? pr[k].y : 0;
        }
        v4f Ri[GRP3], Rj[GRP3];
#pragma unroll
        for (int k = 0; k < GRP3; ++k) { Ri[k] = Rp[pr[k].x]; Rj[k] = Rp[pr[k].y]; }
#pragma unroll
        for (int k = 0; k < GRP3; ++k)
            lj_body(Ri[k], Rj[k], eps, s2, cut2, pr[k].x, energy, forces);
    }
}

// ---------------- fallback A: R12 fused kernel ------------------------------
__device__ __forceinline__ void filt_sel(const unsigned* __restrict__ lds32,
                                         int* __restrict__ is8,
                                         int* __restrict__ js8)
{
#pragma unroll
    for (int k = 0; k < GRP; ++k) {
        unsigned ci = cell6w(lds32, (unsigned)is8[k]);
        unsigned cj = cell6w(lds32, (unsigned)js8[k]);
        int ddx = (int)(ci & 7u) - (int)(cj & 7u);
        int ddy = (int)(ci >> 3) - (int)(cj >> 3);
        bool ok = ((unsigned)(ddx + 1) <= 2u) & ((unsigned)(ddy + 1) <= 2u);
        is8[k] = ok ? is8[k] : 0;
        js8[k] = ok ? js8[k] : 0;
    }
}

__global__ void __launch_bounds__(WGT, 4) lj_fused_kernel(
    const v4f* __restrict__ Rp,
    const unsigned* __restrict__ packed,
    const int* __restrict__ idx_i,
    const int* __restrict__ idx_j,
    const float* __restrict__ eps_p,
    const float* __restrict__ sig_p,
    const float* __restrict__ cut_p,
    float* __restrict__ energy,
    float* __restrict__ forces,
    int n_pairs, int pk_words, int chunk)
{
    extern __shared__ unsigned lds[];
    for (int w = threadIdx.x; w < pk_words; w += WGT)
        lds[w] = packed[w];
    __syncthreads();

    const float eps  = eps_p[0];
    const float sig  = sig_p[0];
    const float cut  = cut_p[0];
    const float s2   = sig * sig;
    const float cut2 = cut * cut;

    const int cs = blockIdx.x * chunk;
    const int ce = min(cs + chunk, n_pairs);
    const int STRIDE = WGT * GRP;

    int p0 = cs + (int)threadIdx.x * GRP;
    if (p0 >= ce) return;

    int isA[GRP], jsA[GRP], isB[GRP], jsB[GRP];
    load_grp(idx_i, idx_j, p0, n_pairs, isA, jsA);
    filt_sel(lds, isA, jsA);
    int p1 = p0 + STRIDE;

    while (true) {
        const bool h1 = p1 < ce;
        if (h1) load_grp(idx_i, idx_j, p1, n_pairs, isB, jsB);
        v4f Ri[GRP], Rj[GRP];
#pragma unroll
        for (int k = 0; k < GRP; ++k) { Ri[k] = Rp[isA[k]]; Rj[k] = Rp[jsA[k]]; }
        if (h1) filt_sel(lds, isB, jsB);
#pragma unroll
        for (int k = 0; k < GRP; ++k)
            lj_body(Ri[k], Rj[k], eps, s2, cut2, isA[k], energy, forces);
        if (!h1) break;
#pragma unroll
        for (int k = 0; k < GRP; ++k) { isA[k] = isB[k]; jsA[k] = jsB[k]; }
        p1 += STRIDE;
    }
}

// ---------------- fallback B: R2 structure ----------------------------------
#define PPT 8
__global__ void __launch_bounds__(256) lj_pairs_fb_kernel(
    const v4f* __restrict__ Rp,
    const v4i* __restrict__ idx_i4, const v4i* __restrict__ idx_j4,
    const float* __restrict__ eps_p, const float* __restrict__ sig_p,
    const float* __restrict__ cut_p,
    float* __restrict__ energy, float* __restrict__ forces, int n_oct)
{
    int t = blockIdx.x * blockDim.x + threadIdx.x;
    if (t >= n_oct) return;
    const float eps  = eps_p[0];
    const float sig  = sig_p[0];
    const float cut  = cut_p[0];
    const float s2   = sig * sig;
    const float cut2 = cut * cut;
    v4i ii0 = __builtin_nontemporal_load(idx_i4 + 2 * t);
    v4i ii1 = __builtin_nontemporal_load(idx_i4 + 2 * t + 1);
    v4i jj0 = __builtin_nontemporal_load(idx_j4 + 2 * t);
    v4i jj1 = __builtin_nontemporal_load(idx_j4 + 2 * t + 1);
    int is[PPT] = { ii0.x, ii0.y, ii0.z, ii0.w, ii1.x, ii1.y, ii1.z, ii1.w };
    int js[PPT] = { jj0.x, jj0.y, jj0.z, jj0.w, jj1.x, jj1.y, jj1.z, jj1.w };
    v4f Ri[PPT], Rj[PPT];
#pragma unroll
    for (int k = 0; k < PPT; ++k) Ri[k] = Rp[is[k]];
#pragma unroll
    for (int k = 0; k < PPT; ++k) Rj[k] = Rp[js[k]];
#pragma unroll
    for (int k = 0; k < PPT; ++k)
        lj_body(Ri[k], Rj[k], eps, s2, cut2, is[k], energy, forces);
}

__global__ void lj_pairs_fb_tail_kernel(
    const v4f* __restrict__ Rp,
    const int* __restrict__ idx_i, const int* __restrict__ idx_j,
    const float* __restrict__ eps_p, const float* __restrict__ sig_p,
    const float* __restrict__ cut_p,
    float* __restrict__ energy, float* __restrict__ forces,
    int start, int n_pairs)
{
    int p = start + blockIdx.x * blockDim.x + threadIdx.x;
    if (p >= n_pairs) return;
    const float eps = eps_p[0];
    const float sig = sig_p[0];
    const float cut = cut_p[0];
    lj_body(Rp[idx_i[p]], Rp[idx_j[p]], eps, sig * sig, cut * cut,
            idx_i[p], energy, forces);
}
// -----------------------------------------------------------------------------

extern "C" void kernel_launch(void* const* d_in, const int* in_sizes, int n_in,
                              void* d_out, int out_size, void* d_ws, size_t ws_size,
                              hipStream_t stream) {
    const float* R     = (const float*)d_in[0];
    const float* eps_p = (const float*)d_in[1];
    const float* sig_p = (const float*)d_in[2];
    const float* cut_p = (const float*)d_in[3];
    const int*   idx_i = (const int*)d_in[4];
    const int*   idx_j = (const int*)d_in[5];

    const int n_atoms = in_sizes[0] / 3;
    const int n_pairs = in_sizes[4];

    float* energy = (float*)d_out;
    float* forces = (float*)d_out + n_atoms;

    // d_out re-poisoned 0xAA before every timed call — zero it.
    (void)hipMemsetAsync(d_out, 0, (size_t)out_size * sizeof(float), stream);

    // split ws layout: [Rp][pkY][pkX][pkZ][counts1][counts2][list]
    char* ws = (char*)d_ws;
    const size_t rp_b      = (((size_t)n_atoms * 16) + 255) & ~(size_t)255;
    const int    pk3_words = (n_atoms + 9) / 10;
    const size_t pk3_b     = (((size_t)pk3_words * 4) + 255) & ~(size_t)255;
    const size_t ct_b      = (((size_t)NWG_S * 4) + 255) & ~(size_t)255;
    const int    chunk     = (((n_pairs + NWG_S - 1) / NWG_S) + GRP - 1)
                             & ~(GRP - 1);
    const size_t list_b    = (size_t)NWG_S * (size_t)chunk * 8;
    const size_t lds3_b    = (((size_t)(pk3_words + 1) * 4) + 15) & ~(size_t)15;

    // fused-fallback ws layout: [Rp][packed xy]
    const int    pk_words  = (n_atoms + 4) / 5;
    const size_t pk_b      = (((size_t)pk_words * 4) + 255) & ~(size_t)255;
    const size_t ldsF_b    = (((size_t)pk_words * 4) + 15) & ~(size_t)15;

    const bool have_rp   = ws_size >= rp_b;
    const bool use_split = have_rp && (lds3_b <= 81920)   // 2 WG/CU needed
        && (ws_size >= rp_b + 3 * pk3_b + 2 * ct_b + list_b);
    const bool use_fused = !use_split && have_rp
        && (ldsF_b <= 160 * 1024) && (ws_size >= rp_b + pk_b);

    if (use_split) {
        v4f*      Rp      = (v4f*)ws;
        unsigned* pkY     = (unsigned*)(ws + rp_b);
        unsigned* pkX     = (unsigned*)(ws + rp_b + pk3_b);
        unsigned* pkZ     = (unsigned*)(ws + rp_b + 2 * pk3_b);
        int*      counts1 = (int*)(ws + rp_b + 3 * pk3_b);
        int*      counts2 = (int*)(ws + rp_b + 3 * pk3_b + ct_b);
        int2*     list    = (int2*)(ws + rp_b + 3 * pk3_b + 2 * ct_b);

        int pblocks = (pk3_words + 255) / 256;
        prep3_kernel<<<pblocks, 256, 0, stream>>>(
            R, cut_p, Rp, pkY, pkX, pkZ, n_atoms);

        (void)hipFuncSetAttribute((const void*)filter_y_kernel,
                                  hipFuncAttributeMaxDynamicSharedMemorySize,
                                  (int)lds3_b);
        filter_y_kernel<<<NWG_S, WGT, lds3_b, stream>>>(
            pkY, idx_i, idx_j, list, counts1, n_pairs, pk3_words, chunk);

        (void)hipFuncSetAttribute((const void*)filter_x_kernel,
                                  hipFuncAttributeMaxDynamicSharedMemorySize,
                                  (int)lds3_b);
        filter_x_kernel<<<NWG_S, WGT, lds3_b, stream>>>(
            pkX, list, counts1, counts2, pk3_words, chunk);

        (void)hipFuncSetAttribute((const void*)lj_z_kernel,
                                  hipFuncAttributeMaxDynamicSharedMemorySize,
                                  (int)lds3_b);
        lj_z_kernel<<<NWG_S, WGT, lds3_b, stream>>>(
            pkZ, Rp, list, counts2, eps_p, sig_p, cut_p,
            energy, forces, pk3_words, chunk);
    } else if (use_fused) {
        v4f*      Rp     = (v4f*)ws;
        unsigned* packed = (unsigned*)(ws + rp_b);

        int pblocks = (pk_words + 255) / 256;
        prep_kernel<<<pblocks, 256, 0, stream>>>(R, cut_p, Rp, packed, n_atoms);

        (void)hipFuncSetAttribute((const void*)lj_fused_kernel,
                                  hipFuncAttributeMaxDynamicSharedMemorySize,
                                  (int)ldsF_b);
        int chunkF = (((n_pairs + NWG_F - 1) / NWG_F) + GRP - 1) & ~(GRP - 1);
        lj_fused_kernel<<<NWG_F, WGT, ldsF_b, stream>>>(
            Rp, packed, idx_i, idx_j, eps_p, sig_p, cut_p,
            energy, forces, n_pairs, pk_words, chunkF);
    } else if (have_rp) {
        v4f* Rp = (v4f*)ws;
        int blocks = (n_atoms + 255) / 256;
        pad_R_kernel<<<blocks, 256, 0, stream>>>(R, Rp, n_atoms);
        const int n_oct = n_pairs / PPT;
        const int start = n_oct * PPT;
        if (n_oct > 0) {
            int fblocks = (n_oct + 255) / 256;
            lj_pairs_fb_kernel<<<fblocks, 256, 0, stream>>>(
                Rp, (const v4i*)idx_i, (const v4i*)idx_j,
                eps_p, sig_p, cut_p, energy, forces, n_oct);
        }
        if (start < n_pairs) {
            lj_pairs_fb_tail_kernel<<<1, 64, 0, stream>>>(
                Rp, idx_i, idx_j, eps_p, sig_p, cut_p,
                energy, forces, start, n_pairs);
        }
    }
}

// Round 6
// 191.046 us; speedup vs baseline: 2.4409x; 1.1589x over previous
//
#include <hip/hip_runtime.h>
#include <stdint.h>

// LJ 12-6 over a neighbor list — round 16: packed-f32 atomics + staging.
// History: R2 direct-gather 131 us. R10/R12 fused 6x6 xy LDS filter 74 us
// (16 waves; source pipelining can't beat compiler vmcnt serialization).
// R13/R15 splits: every list-consumer kernel pins at ~53 us regardless of
// gather count (R13: 5.0M gathers = 53.0us; R15: 2.3M gathers = 53.5us),
// with IDENTICAL WRITE_SIZE = 25.597 MB across ALL variants = ~993k
// device-scope atomicAdds x ~32B fabric granule. => ATOMIC CEILING ~18.7
// G ops/s is the floor; fused 74 = 53 atomic floor + ~20 non-overlapped
// front-end. Total ~= kernel_sum + ~100us fixed harness overhead.
// This round: halve atomic transactions via global_atomic_pk_add_f32
// (2xf32 per op) into a float4-interleaved staging buffer st[atom] =
// (e,fx,fy,fz): 2 pk ops/pair instead of 4 scalar; both ops hit one 32B
// granule. finalize kernel converts staging -> output layout with pure
// stores (d_out memset no longer needed; memset the 3.2MB staging instead).
// Predicted: fused WRITE_SIZE 25.6 -> ~14MB, dur 74 -> ~55-62.

typedef int   v4i __attribute__((ext_vector_type(4)));
typedef float v4f __attribute__((ext_vector_type(4)));
typedef float v2f __attribute__((ext_vector_type(2)));

#define GRP    8
#define WGT    1024
#define NWG_F  256

// ---------------- packed f32x2 atomic add (gfx90a+/gfx950) ------------------
#if __has_builtin(__builtin_amdgcn_global_atomic_fadd_v2f32)
__device__ __forceinline__ void pk_atomic_add(float* p, float a, float b) {
    typedef __attribute__((address_space(1))) v2f gv2f;
    v2f v; v.x = a; v.y = b;
    (void)__builtin_amdgcn_global_atomic_fadd_v2f32((gv2f*)(uintptr_t)p, v);
}
#else
__device__ __forceinline__ void pk_atomic_add(float* p, float a, float b) {
    atomicAdd(p, a);
    atomicAdd(p + 1, b);
}
#endif

// ---------------- prep: pad R to float4 AND build packed xy cell table ------
// 5 atoms per 32-bit word, 6 bits each (cx | cy<<3, cells of size cutoff,
// clamped 0..7). Clamp is monotone -> conservative (correct) for ANY box.
__global__ void __launch_bounds__(256) prep_kernel(
    const float* __restrict__ R, const float* __restrict__ cut_p,
    v4f* __restrict__ Rp, unsigned* __restrict__ packed, int n_atoms)
{
    int t = blockIdx.x * blockDim.x + threadIdx.x;
    int n_grp = (n_atoms + 4) / 5;
    if (t >= n_grp) return;
    const float inv_cut = 1.0f / cut_p[0];
    int a0 = t * 5;
    unsigned w = 0u;
#pragma unroll
    for (int k = 0; k < 5; ++k) {
        int a = a0 + k;
        if (a < n_atoms) {
            float x = R[3 * a + 0];
            float y = R[3 * a + 1];
            float z = R[3 * a + 2];
            v4f v; v.x = x; v.y = y; v.z = z; v.w = 0.0f;
            Rp[a] = v;  // 16B aligned: single-transaction gathers later
            int cx = min(7, max(0, (int)(x * inv_cut)));
            int cy = min(7, max(0, (int)(y * inv_cut)));
            w |= (unsigned)(cx | (cy << 3)) << (6 * k);
        }
        // padded atoms keep cell 0; (0,0) pairs rejected by r2>1e-10
    }
    packed[t] = w;
}

// standalone pad for the fallback path
__global__ void __launch_bounds__(256) pad_R_kernel(
    const float* __restrict__ R, v4f* __restrict__ Rp, int n_atoms)
{
    int a = blockIdx.x * blockDim.x + threadIdx.x;
    if (a < n_atoms) {
        v4f v;
        v.x = R[3 * a + 0];
        v.y = R[3 * a + 1];
        v.z = R[3 * a + 2];
        v.w = 0.0f;
        Rp[a] = v;
    }
}

// one aligned ds_read_b32 per lookup: word = a/5 (magic mul), shift = (a%5)*6
__device__ __forceinline__ unsigned cell6w(const unsigned* __restrict__ lds32,
                                           unsigned a) {
    unsigned q = __umulhi(a, 0xCCCCCCCDu) >> 2;   // a / 5, exact for all u32
    unsigned r = a - q * 5u;                       // a % 5
    return (lds32[q] >> (r * 6u)) & 63u;
}

__device__ __forceinline__ void load_grp(
    const int* __restrict__ idx_i, const int* __restrict__ idx_j,
    int p, int n_pairs, int* __restrict__ is8, int* __restrict__ js8)
{
    if (p + GRP <= n_pairs) {   // p % 8 == 0 -> int4-aligned fast path
        v4i a0 = __builtin_nontemporal_load((const v4i*)idx_i + (p >> 2));
        v4i a1 = __builtin_nontemporal_load((const v4i*)idx_i + (p >> 2) + 1);
        v4i b0 = __builtin_nontemporal_load((const v4i*)idx_j + (p >> 2));
        v4i b1 = __builtin_nontemporal_load((const v4i*)idx_j + (p >> 2) + 1);
        is8[0] = a0.x; is8[1] = a0.y; is8[2] = a0.z; is8[3] = a0.w;
        is8[4] = a1.x; is8[5] = a1.y; is8[6] = a1.z; is8[7] = a1.w;
        js8[0] = b0.x; js8[1] = b0.y; js8[2] = b0.z; js8[3] = b0.w;
        js8[4] = b1.x; js8[5] = b1.y; js8[6] = b1.z; js8[7] = b1.w;
    } else {
#pragma unroll
        for (int k = 0; k < GRP; ++k) {
            bool v = (p + k < n_pairs);
            is8[k] = v ? idx_i[p + k] : 0;
            js8[k] = v ? idx_j[p + k] : 0;
            // padded entries: i==j==0 -> r2==0 -> rejected by r2>1e-10
        }
    }
}

// filter-and-select: failing pairs get index 0 (broadcast gather of Rp[0];
// Rp[0]-Rp[0] -> r2=0 -> rejected downstream). Constant VMEM issue count.
__device__ __forceinline__ void filt_sel(const unsigned* __restrict__ lds32,
                                         int* __restrict__ is8,
                                         int* __restrict__ js8)
{
#pragma unroll
    for (int k = 0; k < GRP; ++k) {
        unsigned ci = cell6w(lds32, (unsigned)is8[k]);
        unsigned cj = cell6w(lds32, (unsigned)js8[k]);
        int ddx = (int)(ci & 7u) - (int)(cj & 7u);
        int ddy = (int)(ci >> 3) - (int)(cj >> 3);
        bool ok = ((unsigned)(ddx + 1) <= 2u) & ((unsigned)(ddy + 1) <= 2u);
        is8[k] = ok ? is8[k] : 0;   // v_cndmask, no branch
        js8[k] = ok ? js8[k] : 0;
    }
}

// staged accumulation: st[atom] = (e, fx, fy, fz), 2 pk atomics per pair
__device__ __forceinline__ void lj_body_st(
    v4f A, v4f B, float eps, float s2, float cut2, int gi,
    float* __restrict__ st)
{
    const float dx = A.x - B.x, dy = A.y - B.y, dz = A.z - B.z;
    const float r2 = dx * dx + dy * dy + dz * dz;
    if (r2 < cut2 && r2 > 1e-10f) {
        const float inv  = 1.0f / r2;
        const float sr2  = s2 * inv;
        const float sr6  = sr2 * sr2 * sr2;
        const float sr12 = sr6 * sr6;
        const float e    = 2.0f * eps * (sr12 - sr6);              // 0.5 * 4eps
        const float f    = 24.0f * eps * (2.0f * sr12 - sr6) * inv;
        float* p = st + ((size_t)(unsigned)gi << 2);
        pk_atomic_add(p,     e,      f * dx);
        pk_atomic_add(p + 2, f * dy, f * dz);
    }
}

// legacy direct-output accumulation (fallback paths)
__device__ __forceinline__ void lj_body(
    v4f A, v4f B, float eps, float s2, float cut2, int gi,
    float* __restrict__ energy, float* __restrict__ forces)
{
    const float dx = A.x - B.x, dy = A.y - B.y, dz = A.z - B.z;
    const float r2 = dx * dx + dy * dy + dz * dz;
    if (r2 < cut2 && r2 > 1e-10f) {
        const float inv  = 1.0f / r2;
        const float sr2  = s2 * inv;
        const float sr6  = sr2 * sr2 * sr2;
        const float sr12 = sr6 * sr6;
        const float e    = 2.0f * eps * (sr12 - sr6);
        const float f    = 24.0f * eps * (2.0f * sr12 - sr6) * inv;
        atomicAdd(&energy[gi], e);
        atomicAdd(&forces[3 * gi + 0], f * dx);
        atomicAdd(&forces[3 * gi + 1], f * dy);
        atomicAdd(&forces[3 * gi + 2], f * dz);
    }
}

// Fused (R12 structure): prefetch-next / gather-current / filter-next /
// compute-current; constant VMEM issue per iteration.
__global__ void __launch_bounds__(WGT, 4) lj_fused_st_kernel(
    const v4f* __restrict__ Rp,
    const unsigned* __restrict__ packed,
    const int* __restrict__ idx_i,
    const int* __restrict__ idx_j,
    const float* __restrict__ eps_p,
    const float* __restrict__ sig_p,
    const float* __restrict__ cut_p,
    float* __restrict__ st,
    int n_pairs, int pk_words, int chunk)
{
    extern __shared__ unsigned lds[];
    for (int w = threadIdx.x; w < pk_words; w += WGT)
        lds[w] = packed[w];
    __syncthreads();

    const float eps  = eps_p[0];
    const float sig  = sig_p[0];
    const float cut  = cut_p[0];
    const float s2   = sig * sig;
    const float cut2 = cut * cut;

    const int cs = blockIdx.x * chunk;
    const int ce = min(cs + chunk, n_pairs);
    const int STRIDE = WGT * GRP;

    int p0 = cs + (int)threadIdx.x * GRP;
    if (p0 >= ce) return;

    int isA[GRP], jsA[GRP], isB[GRP], jsB[GRP];

    load_grp(idx_i, idx_j, p0, n_pairs, isA, jsA);
    filt_sel(lds, isA, jsA);
    int p1 = p0 + STRIDE;

    while (true) {
        const bool h1 = p1 < ce;

        if (h1) load_grp(idx_i, idx_j, p1, n_pairs, isB, jsB);

        v4f Ri[GRP], Rj[GRP];
#pragma unroll
        for (int k = 0; k < GRP; ++k) { Ri[k] = Rp[isA[k]]; Rj[k] = Rp[jsA[k]]; }

        if (h1) filt_sel(lds, isB, jsB);

#pragma unroll
        for (int k = 0; k < GRP; ++k)
            lj_body_st(Ri[k], Rj[k], eps, s2, cut2, isA[k], st);

        if (!h1) break;
#pragma unroll
        for (int k = 0; k < GRP; ++k) { isA[k] = isB[k]; jsA[k] = jsB[k]; }
        p1 += STRIDE;
    }
}

// staging -> output layout, pure stores (covers every element of d_out)
__global__ void __launch_bounds__(256) finalize_kernel(
    const v4f* __restrict__ st, float* __restrict__ energy,
    float* __restrict__ forces, int n_atoms)
{
    int a = blockIdx.x * blockDim.x + threadIdx.x;
    if (a < n_atoms) {
        v4f s = st[a];
        energy[a]          = s.x;
        forces[3 * a + 0]  = s.y;
        forces[3 * a + 1]  = s.z;
        forces[3 * a + 2]  = s.w;
    }
}

// ---------------- fallback A: R12 fused kernel (direct atomics) -------------
__global__ void __launch_bounds__(WGT, 4) lj_fused_kernel(
    const v4f* __restrict__ Rp,
    const unsigned* __restrict__ packed,
    const int* __restrict__ idx_i,
    const int* __restrict__ idx_j,
    const float* __restrict__ eps_p,
    const float* __restrict__ sig_p,
    const float* __restrict__ cut_p,
    float* __restrict__ energy,
    float* __restrict__ forces,
    int n_pairs, int pk_words, int chunk)
{
    extern __shared__ unsigned lds[];
    for (int w = threadIdx.x; w < pk_words; w += WGT)
        lds[w] = packed[w];
    __syncthreads();

    const float eps  = eps_p[0];
    const float sig  = sig_p[0];
    const float cut  = cut_p[0];
    const float s2   = sig * sig;
    const float cut2 = cut * cut;

    const int cs = blockIdx.x * chunk;
    const int ce = min(cs + chunk, n_pairs);
    const int STRIDE = WGT * GRP;

    int p0 = cs + (int)threadIdx.x * GRP;
    if (p0 >= ce) return;

    int isA[GRP], jsA[GRP], isB[GRP], jsB[GRP];
    load_grp(idx_i, idx_j, p0, n_pairs, isA, jsA);
    filt_sel(lds, isA, jsA);
    int p1 = p0 + STRIDE;

    while (true) {
        const bool h1 = p1 < ce;
        if (h1) load_grp(idx_i, idx_j, p1, n_pairs, isB, jsB);
        v4f Ri[GRP], Rj[GRP];
#pragma unroll
        for (int k = 0; k < GRP; ++k) { Ri[k] = Rp[isA[k]]; Rj[k] = Rp[jsA[k]]; }
        if (h1) filt_sel(lds, isB, jsB);
#pragma unroll
        for (int k = 0; k < GRP; ++k)
            lj_body(Ri[k], Rj[k], eps, s2, cut2, isA[k], energy, forces);
        if (!h1) break;
#pragma unroll
        for (int k = 0; k < GRP; ++k) { isA[k] = isB[k]; jsA[k] = jsB[k]; }
        p1 += STRIDE;
    }
}

// ---------------- fallback B: R2 structure ----------------------------------
#define PPT 8
__global__ void __launch_bounds__(256) lj_pairs_fb_kernel(
    const v4f* __restrict__ Rp,
    const v4i* __restrict__ idx_i4, const v4i* __restrict__ idx_j4,
    const float* __restrict__ eps_p, const float* __restrict__ sig_p,
    const float* __restrict__ cut_p,
    float* __restrict__ energy, float* __restrict__ forces, int n_oct)
{
    int t = blockIdx.x * blockDim.x + threadIdx.x;
    if (t >= n_oct) return;
    const float eps  = eps_p[0];
    const float sig  = sig_p[0];
    const float cut  = cut_p[0];
    const float s2   = sig * sig;
    const float cut2 = cut * cut;
    v4i ii0 = __builtin_nontemporal_load(idx_i4 + 2 * t);
    v4i ii1 = __builtin_nontemporal_load(idx_i4 + 2 * t + 1);
    v4i jj0 = __builtin_nontemporal_load(idx_j4 + 2 * t);
    v4i jj1 = __builtin_nontemporal_load(idx_j4 + 2 * t + 1);
    int is[PPT] = { ii0.x, ii0.y, ii0.z, ii0.w, ii1.x, ii1.y, ii1.z, ii1.w };
    int js[PPT] = { jj0.x, jj0.y, jj0.z, jj0.w, jj1.x, jj1.y, jj1.z, jj1.w };
    v4f Ri[PPT], Rj[PPT];
#pragma unroll
    for (int k = 0; k < PPT; ++k) Ri[k] = Rp[is[k]];
#pragma unroll
    for (int k = 0; k < PPT; ++k) Rj[k] = Rp[js[k]];
#pragma unroll
    for (int k = 0; k < PPT; ++k)
        lj_body(Ri[k], Rj[k], eps, s2, cut2, is[k], energy, forces);
}

__global__ void lj_pairs_fb_tail_kernel(
    const v4f* __restrict__ Rp,
    const int* __restrict__ idx_i, const int* __restrict__ idx_j,
    const float* __restrict__ eps_p, const float* __restrict__ sig_p,
    const float* __restrict__ cut_p,
    float* __restrict__ energy, float* __restrict__ forces,
    int start, int n_pairs)
{
    int p = start + blockIdx.x * blockDim.x + threadIdx.x;
    if (p >= n_pairs) return;
    const float eps = eps_p[0];
    const float sig = sig_p[0];
    const float cut = cut_p[0];
    lj_body(Rp[idx_i[p]], Rp[idx_j[p]], eps, sig * sig, cut * cut,
            idx_i[p], energy, forces);
}
// -----------------------------------------------------------------------------

extern "C" void kernel_launch(void* const* d_in, const int* in_sizes, int n_in,
                              void* d_out, int out_size, void* d_ws, size_t ws_size,
                              hipStream_t stream) {
    const float* R     = (const float*)d_in[0];
    const float* eps_p = (const float*)d_in[1];
    const float* sig_p = (const float*)d_in[2];
    const float* cut_p = (const float*)d_in[3];
    const int*   idx_i = (const int*)d_in[4];
    const int*   idx_j = (const int*)d_in[5];

    const int n_atoms = in_sizes[0] / 3;
    const int n_pairs = in_sizes[4];

    float* energy = (float*)d_out;
    float* forces = (float*)d_out + n_atoms;

    // ws layout: [Rp float4][packed cell table][staging float4]
    char* ws = (char*)d_ws;
    const size_t rp_b     = (((size_t)n_atoms * 16) + 255) & ~(size_t)255;
    const int    pk_words = (n_atoms + 4) / 5;
    const size_t pk_b     = (((size_t)pk_words * 4) + 255) & ~(size_t)255;
    const size_t st_b     = (((size_t)n_atoms * 16) + 255) & ~(size_t)255;
    const size_t lds_b    = (((size_t)pk_words * 4) + 15) & ~(size_t)15;

    const bool have_rp  = ws_size >= rp_b;
    const bool lds_ok   = lds_b <= 160000;
    const bool use_st   = have_rp && lds_ok
                          && (ws_size >= rp_b + pk_b + st_b);
    const bool use_old  = !use_st && have_rp && lds_ok
                          && (ws_size >= rp_b + pk_b);

    v4f*      Rp     = (v4f*)ws;
    unsigned* packed = (unsigned*)(ws + rp_b);
    float*    st     = (float*)(ws + rp_b + pk_b);

    if (use_st) {
        // staging accumulator zeroed each call; d_out fully overwritten by
        // finalize (no d_out memset needed).
        (void)hipMemsetAsync(st, 0, (size_t)n_atoms * 16, stream);

        int pblocks = (pk_words + 255) / 256;
        prep_kernel<<<pblocks, 256, 0, stream>>>(R, cut_p, Rp, packed, n_atoms);

        (void)hipFuncSetAttribute((const void*)lj_fused_st_kernel,
                                  hipFuncAttributeMaxDynamicSharedMemorySize,
                                  (int)lds_b);
        int chunk = (((n_pairs + NWG_F - 1) / NWG_F) + GRP - 1) & ~(GRP - 1);
        lj_fused_st_kernel<<<NWG_F, WGT, lds_b, stream>>>(
            Rp, packed, idx_i, idx_j, eps_p, sig_p, cut_p,
            st, n_pairs, pk_words, chunk);

        int fblocks = (n_atoms + 255) / 256;
        finalize_kernel<<<fblocks, 256, 0, stream>>>(
            (const v4f*)st, energy, forces, n_atoms);
    } else if (use_old) {
        (void)hipMemsetAsync(d_out, 0, (size_t)out_size * sizeof(float), stream);

        int pblocks = (pk_words + 255) / 256;
        prep_kernel<<<pblocks, 256, 0, stream>>>(R, cut_p, Rp, packed, n_atoms);

        (void)hipFuncSetAttribute((const void*)lj_fused_kernel,
                                  hipFuncAttributeMaxDynamicSharedMemorySize,
                                  (int)lds_b);
        int chunk = (((n_pairs + NWG_F - 1) / NWG_F) + GRP - 1) & ~(GRP - 1);
        lj_fused_kernel<<<NWG_F, WGT, lds_b, stream>>>(
            Rp, packed, idx_i, idx_j, eps_p, sig_p, cut_p,
            energy, forces, n_pairs, pk_words, chunk);
    } else if (have_rp) {
        (void)hipMemsetAsync(d_out, 0, (size_t)out_size * sizeof(float), stream);

        int blocks = (n_atoms + 255) / 256;
        pad_R_kernel<<<blocks, 256, 0, stream>>>(R, Rp, n_atoms);
        const int n_oct = n_pairs / PPT;
        const int start = n_oct * PPT;
        if (n_oct > 0) {
            int fblocks = (n_oct + 255) / 256;
            lj_pairs_fb_kernel<<<fblocks, 256, 0, stream>>>(
                Rp, (const v4i*)idx_i, (const v4i*)idx_j,
                eps_p, sig_p, cut_p, energy, forces, n_oct);
        }
        if (start < n_pairs) {
            lj_pairs_fb_tail_kernel<<<1, 64, 0, stream>>>(
                Rp, idx_i, idx_j, eps_p, sig_p, cut_p,
                energy, forces, start, n_pairs);
        }
    }
}